// Round 2
// baseline (1302.687 us; speedup 1.0000x reference)
//
#include <hip/hip_runtime.h>
#include <hip/hip_bf16.h>

// SLSTM recurrence + Linear.  B=1024, T=2048, IN=16, H=128, OUT=1.
// R13 = R12 + dependency-flattened K-reduction:
//   Each gate's K=128 h-GEMM = TWO independent depth-2 MFMA chains
//   (chain A: kf0->kf1 seeded accN(bias+x); chain B: kf2->kf3 seeded 0),
//   merged with one f32x4 add before pack4. Removes the depth-4 dependent
//   MFMA stalls (~40-50 cyc result latency each) that R12's counters showed
//   as the dominant non-issue bubble (722 cyc MFMA issue + ~150 VALU issue
//   vs 1435 cyc step => ~550 cyc latency stall).
//   Merge adds + packs + exp2 of g,i,f pinned 1 MFMA : 2 VALU into the
//   tail+accN issue window (12 MFMAs ~ 430 cyc of slots) via SGB.
// Structure: 256 WGs x 512 thr (8 waves = 2/SIMD), 4 batch rows/WG, all 256
// CUs, zero cross-CU traffic. Wave owns col-group wv x 4 gates; accs packed
// 4->1 lane-dense via 3-dpp chain; 1 elem/lane. MFMA issue floor ~722 cyc
// (fill-4 invariant: any row/WG repartition keeps per-SIMD MFMA time const).

#define T_LEN 2048
#define IN_DIM 16
#define CHUNK 32
#define NROWS 4

typedef __attribute__((ext_vector_type(4))) float f32x4;
typedef __attribute__((ext_vector_type(8))) short s16x8;

__device__ __forceinline__ short f2bf(float f) {
    union { float f; unsigned u; } v; v.f = f;
    unsigned r = v.u + 0x7fffu + ((v.u >> 16) & 1u);   // RNE
    return (short)(r >> 16);
}
__device__ __forceinline__ unsigned pk_bf16(float a, float b) {
#if __has_builtin(__builtin_amdgcn_cvt_pk_bf16_f32)
    typedef __attribute__((ext_vector_type(2))) __bf16 bf16x2;
    bf16x2 r = __builtin_amdgcn_cvt_pk_bf16_f32(a, b);
    union { bf16x2 v; unsigned u; } c; c.v = r;
    return c.u;
#else
    return (unsigned)(unsigned short)f2bf(a) | ((unsigned)(unsigned short)f2bf(b) << 16);
#endif
}
// merge quarter-dense regs: lanes 0-3 keep r0; 4-7 <- r1[0-3]; 8-11 <- r2[0-3];
// 12-15 <- r3[0-3].  row_ror:n pulls from lane (i-n) mod 16 (verified R10).
__device__ __forceinline__ float pack4(float r0, float r1, float r2, float r3) {
    int d = __float_as_int(r0);
    d = __builtin_amdgcn_update_dpp(d, __float_as_int(r1), 0x124, 0xF, 0x2, false);
    d = __builtin_amdgcn_update_dpp(d, __float_as_int(r2), 0x128, 0xF, 0x4, false);
    d = __builtin_amdgcn_update_dpp(d, __float_as_int(r3), 0x12C, 0xF, 0x8, false);
    return __int_as_float(d);
}

__global__ __launch_bounds__(512, 2)
void slstm_persistent(const float* __restrict__ x,
                      const float* __restrict__ W_ih,
                      const float* __restrict__ W_hh,
                      const float* __restrict__ b_ih,
                      const float* __restrict__ b_hh,
                      const float* __restrict__ fc_w,
                      const float* __restrict__ fc_b,
                      float* __restrict__ out)
{
    // h: element (col, nb) at shorts[(col>>5)*128 + ((col>>3)&3)*32 + nb*8 + (col&7)]
    // = frag-ordered for the B-operand; the 16 valid reader lanes span all 32
    // banks exactly twice -> conflict-free. 1 KB/buf.
    __shared__ __align__(16) unsigned short h_frag[2][512];
    // x frags [buf][slot][qh 2][n 4][j 8] bf16, dbuf (8 KB)
    __shared__ __align__(16) unsigned short xlds[2][CHUNK][2][4][8];
    __shared__ float red[NROWS];

    const int tid  = threadIdx.x;
    const int lane = tid & 63;
    const int wv   = tid >> 6;          // wave 0..7 = col-group
    const int c16  = lane & 15;
    const int quad = lane >> 4;         // 0..3
    const int b0   = blockIdx.x * NROWS;

    const float kNL2E = -1.44269504f;

    // ---- weights pre-scaled; wave owns col-group wv x 4 gates ----
    s16x8 wfrag[4][5];                  // [g][kf], kf4 = x
    f32x4 biasC[4];
    #pragma unroll
    for (int g = 0; g < 4; ++g) {
        const float scale = (g == 2) ? (2.0f * kNL2E) : kNL2E;
        const int n = g * 128 + wv * 16 + c16;
        #pragma unroll
        for (int kf = 0; kf < 5; ++kf) {
            s16x8 fr;
            #pragma unroll
            for (int j = 0; j < 8; ++j) {
                const int k = kf * 32 + quad * 8 + j;
                float v;
                if (kf < 4) v = W_hh[n * 128 + k];
                else {
                    const int kk = k - 128;
                    v = (kk < IN_DIM) ? W_ih[n * IN_DIM + kk] : 0.0f;
                }
                fr[j] = f2bf(v * scale);
            }
            wfrag[g][kf] = fr;
        }
        #pragma unroll
        for (int r = 0; r < 4; ++r) {
            const int m = g * 128 + wv * 16 + quad * 4 + r;
            biasC[g][r] = (b_ih[m] + b_hh[m]) * scale;
        }
    }

    // zero h buf 0 (h0 = 0); buf 1 fully written at t=0 before first read
    if (tid < 256) ((unsigned*)h_frag)[tid] = 0;

    // ---- packed-lane identity: element (col, nb) ----
    const int e    = c16 >> 2;
    const int nb   = c16 & 3;
    const int col  = wv * 16 + quad * 4 + e;
    const int waddr = (col >> 5) * 128 + ((col >> 3) & 3) * 32 + nb * 8 + (col & 7);
    // h read: valid lanes c16<4 read 16B at v*16 (v = quad*4+c16); others addr 0
    const int hoff = (c16 < 4) ? ((quad * 4 + c16) * 16) : 0;   // bytes within frag
    // x read: valid lanes quad<2 && c16<4
    const bool xv = (quad < 2) && (c16 < 4);
    const int xoff  = xv ? (quad * 64 + c16 * 16) : 0;          // bytes
    const int xmask = xv ? ~0 : 0;

    float c_st = 0.0f, h_ep = 0.0f;

    // ---- prologue: stage chunk 0 -> xlds[0]; chunk 1 -> xreg ----
    f32x4 xreg;
    {
        const int flat4 = tid * 4;
        const int b_loc = flat4 >> 9;
        const int rem   = flat4 & 511;
        const float* xr = x + (size_t)(b0 + b_loc) * (T_LEN * IN_DIM);
        f32x4 v4 = *(const f32x4*)(xr + rem);
        const int slot = rem >> 4, feat = rem & 15;
        unsigned* dst = (unsigned*)&xlds[0][slot][feat >> 3][b_loc][feat & 7];
        dst[0] = pk_bf16(v4[0], v4[1]);
        dst[1] = pk_bf16(v4[2], v4[3]);
        xreg = *(const f32x4*)(xr + CHUNK * IN_DIM + rem);
    }
    __syncthreads();

    // accN = bias + x-MFMA, one step ahead
    f32x4 accN[4];
    {
        s16x8 zx0 = *(const s16x8*)((const char*)xlds + (xoff & xmask));
        #pragma unroll
        for (int g = 0; g < 4; ++g)
            accN[g] = __builtin_amdgcn_mfma_f32_16x16x32_bf16(wfrag[g][4], zx0, biasC[g], 0, 0, 0);
    }

    // step: flattened 8x depth-2 MFMA chains + interleaved elementwise
    auto step_impl = [&](const int RB, const int WB, const int t) {
        const char* hb = (const char*)h_frag[RB];
        s16x8 zf[4];
        #pragma unroll
        for (int kf = 0; kf < 4; ++kf)
            zf[kf] = *(const s16x8*)(hb + hoff + kf * 256);
        // x frag for t+1 (independent of h(t)) — load early
        const int ts  = t + 1;
        const int off = (((ts >> 5) & 1) * 4096 + (ts & 31) * 128 + xoff) & xmask;
        s16x8 zxn = *(const s16x8*)((const char*)xlds + off);

        const f32x4 zero4 = {0.f, 0.f, 0.f, 0.f};
        f32x4 aA0 = accN[0], aA1 = accN[1], aA2 = accN[2], aA3 = accN[3];
        f32x4 aB0 = zero4,  aB1 = zero4,  aB2 = zero4,  aB3 = zero4;

        // ---- heads: 8 fully independent MFMAs ----
        aA2 = __builtin_amdgcn_mfma_f32_16x16x32_bf16(wfrag[2][0], zf[0], aA2, 0, 0, 0);
        aB2 = __builtin_amdgcn_mfma_f32_16x16x32_bf16(wfrag[2][2], zf[2], aB2, 0, 0, 0);
        aA0 = __builtin_amdgcn_mfma_f32_16x16x32_bf16(wfrag[0][0], zf[0], aA0, 0, 0, 0);
        aB0 = __builtin_amdgcn_mfma_f32_16x16x32_bf16(wfrag[0][2], zf[2], aB0, 0, 0, 0);
        aA1 = __builtin_amdgcn_mfma_f32_16x16x32_bf16(wfrag[1][0], zf[0], aA1, 0, 0, 0);
        aB1 = __builtin_amdgcn_mfma_f32_16x16x32_bf16(wfrag[1][2], zf[2], aB1, 0, 0, 0);
        aA3 = __builtin_amdgcn_mfma_f32_16x16x32_bf16(wfrag[3][0], zf[0], aA3, 0, 0, 0);
        aB3 = __builtin_amdgcn_mfma_f32_16x16x32_bf16(wfrag[3][2], zf[2], aB3, 0, 0, 0);

        // ---- tails (dep only on a head >=8 issue-slots earlier) + accN ----
        aA2 = __builtin_amdgcn_mfma_f32_16x16x32_bf16(wfrag[2][1], zf[1], aA2, 0, 0, 0);
        aB2 = __builtin_amdgcn_mfma_f32_16x16x32_bf16(wfrag[2][3], zf[3], aB2, 0, 0, 0);
        aA0 = __builtin_amdgcn_mfma_f32_16x16x32_bf16(wfrag[0][1], zf[1], aA0, 0, 0, 0);
        aB0 = __builtin_amdgcn_mfma_f32_16x16x32_bf16(wfrag[0][3], zf[3], aB0, 0, 0, 0);
        aA1 = __builtin_amdgcn_mfma_f32_16x16x32_bf16(wfrag[1][1], zf[1], aA1, 0, 0, 0);
        aB1 = __builtin_amdgcn_mfma_f32_16x16x32_bf16(wfrag[1][3], zf[3], aB1, 0, 0, 0);
        aA3 = __builtin_amdgcn_mfma_f32_16x16x32_bf16(wfrag[3][1], zf[1], aA3, 0, 0, 0);
        aB3 = __builtin_amdgcn_mfma_f32_16x16x32_bf16(wfrag[3][3], zf[3], aB3, 0, 0, 0);
        // accN refresh for t+1 (h-independent — fills the same issue window)
        accN[0] = __builtin_amdgcn_mfma_f32_16x16x32_bf16(wfrag[0][4], zxn, biasC[0], 0, 0, 0);
        accN[1] = __builtin_amdgcn_mfma_f32_16x16x32_bf16(wfrag[1][4], zxn, biasC[1], 0, 0, 0);

        // ---- elementwise front: merges + packs + exp2 of g,i,f ----
        const f32x4 a2v = aA2 + aB2;
        const float dg = pack4(a2v[0], a2v[1], a2v[2], a2v[3]);
        const float eg = __builtin_amdgcn_exp2f(dg);
        const f32x4 a0v = aA0 + aB0;
        const float di = pack4(a0v[0], a0v[1], a0v[2], a0v[3]);
        const float ei = __builtin_amdgcn_exp2f(di);
        const f32x4 a1v = aA1 + aB1;
        const float df = pack4(a1v[0], a1v[1], a1v[2], a1v[3]);
        const float ef = __builtin_amdgcn_exp2f(df);
        const float af  = 1.0f + ef;
        const float t1  = (1.0f + ei) * (1.0f + eg);
        const float num = fmaf(c_st, t1, (1.0f - eg) * af);
        const float den = af * t1;

        // pin: 8 head MFMAs first, then {1 MFMA : 2 VALU} x 10 interleave of
        // tails/accN with the merge-adds+packs+exp2 front-section
        __builtin_amdgcn_sched_group_barrier(0x008, 8, 0);
        #pragma unroll
        for (int kq = 0; kq < 10; ++kq) {
            __builtin_amdgcn_sched_group_barrier(0x008, 1, 0);  // 1 MFMA
            __builtin_amdgcn_sched_group_barrier(0x002, 2, 0);  // 2 VALU
        }
        __builtin_amdgcn_sched_barrier(0);

        // ---- serial tail: c-chain + o-gate + h write ----
        const float cn = num * __builtin_amdgcn_rcpf(den);
        c_st = cn;
        const float ec = __builtin_amdgcn_exp2f(fminf(cn * (2.0f * kNL2E), 40.f));
        const f32x4 a3v = aA3 + aB3;
        const float dojj = pack4(a3v[0], a3v[1], a3v[2], a3v[3]);
        const float eo = __builtin_amdgcn_exp2f(dojj);
        const float hn = (1.0f - ec) * __builtin_amdgcn_rcpf((1.0f + eo) * (1.0f + ec));
        h_ep = hn;
        h_frag[WB][waddr] = (unsigned short)f2bf(hn);   // one ds_write_b16
        // last two accN MFMAs drain across the barrier into the next step's
        // zf-read latency window
        accN[2] = __builtin_amdgcn_mfma_f32_16x16x32_bf16(wfrag[2][4], zxn, biasC[2], 0, 0, 0);
        accN[3] = __builtin_amdgcn_mfma_f32_16x16x32_bf16(wfrag[3][4], zxn, biasC[3], 0, 0, 0);
        __syncthreads();
    };

    for (int t = 0; t < T_LEN; t += 2) {
        step_impl(0, 1, t);

        // ---- spread x maintenance ----
        const int iter  = (t >> 1) & 15;
        const int cbase = t & ~(CHUNK - 1);
        if (iter < 2) {
            if (cbase + CHUNK < T_LEN) {
                const int flat4 = tid * 4;
                const int b_loc = flat4 >> 9;
                const int rem   = flat4 & 511;
                const int slot = rem >> 4, feat = rem & 15;
                const int nb1 = ((cbase >> 5) + 1) & 1;
                unsigned* dst = (unsigned*)&xlds[nb1][slot][feat >> 3][b_loc][(feat & 7) + 2 * iter];
                dst[0] = pk_bf16(xreg[2 * iter], xreg[2 * iter + 1]);
            }
        } else if (iter == 8) {
            const int tnext = cbase + 2 * CHUNK;
            if (tnext < T_LEN) {
                const int flat4 = tid * 4;
                const int b_loc = flat4 >> 9;
                const int rem   = flat4 & 511;
                xreg = *(const f32x4*)(x + (size_t)(b0 + b_loc) * (T_LEN * IN_DIM)
                                         + (size_t)tnext * IN_DIM + rem);
            }
        }

        step_impl(1, 0, t + 1);
    }

    // ---- epilogue: out[b] = sum_cols h * fc_w + fc_b ----
    float v = h_ep * fc_w[col];
    v += __shfl_xor(v, 4);
    v += __shfl_xor(v, 8);
    v += __shfl_xor(v, 16);
    v += __shfl_xor(v, 32);
    if (tid < NROWS) red[tid] = 0.0f;
    __syncthreads();
    if (lane < NROWS) atomicAdd(&red[nb], v);
    __syncthreads();
    if (tid < NROWS) out[b0 + tid] = red[tid] + fc_b[0];
}

extern "C" void kernel_launch(void* const* d_in, const int* in_sizes, int n_in,
                              void* d_out, int out_size, void* d_ws, size_t ws_size,
                              hipStream_t stream) {
    const float* x    = (const float*)d_in[0];
    const float* W_ih = (const float*)d_in[1];
    const float* W_hh = (const float*)d_in[2];
    const float* b_ih = (const float*)d_in[3];
    const float* b_hh = (const float*)d_in[4];
    const float* fc_w = (const float*)d_in[5];
    const float* fc_b = (const float*)d_in[6];
    float* out = (float*)d_out;

    slstm_persistent<<<256, 512, 0, stream>>>(x, W_ih, W_hh, b_ih, b_hh, fc_w, fc_b, out);
}

// Round 3
// 1209.545 us; speedup vs baseline: 1.0770x; 1.0770x over previous
//
#include <hip/hip_runtime.h>
#include <hip/hip_bf16.h>

// SLSTM recurrence + Linear.  B=1024, T=2048, IN=16, H=128, OUT=1.
// R14 = R12 (best, 1175us) + VALU-issue micro-bundle:
//   (1) acc ping-pong: gate chains accumulate IN PLACE on acc_in; x-refresh
//       writes acc_out; arrays alternate per step -> no acc-seed copy movs.
//   (2) h-write via one v_cvt_pk_bf16_f32 instead of 4-instr manual RNE.
//   (3) o-gate pack/exp2 + (1+eo) hoisted BEFORE the c-chain -> post-ec
//       serial depth shrinks ~5 ops (hn = (1-ec)*rcp(p_o*(1+ec))).
//   (4) incremental zxn offset: off = (off+128) & 8191 (byte walk over the
//       2x4KB x dbuf) replaces per-step shift/mask recompute.
// Rationale (R12 counters): step 1435 cyc/SIMD = MFMA issue 722 + VALU busy
// 617, additive; both on the recurrence critical path. Necessary tail VALU
// ~300 cyc/SIMD -> ~300 of compiler fat (copies, f2bf, addressing, late eo).
// R13 lesson: depth-4 chains have no stalls at 2 waves/SIMD (64-cyc gap >=
// dep latency); do NOT flatten, do NOT over-pin.
// Structure: 256 WGs x 512 thr (8 waves = 2/SIMD), 4 batch rows/WG, all 256
// CUs, zero cross-CU traffic. Wave owns col-group wv x 4 gates; accs packed
// 4->1 lane-dense via 3-dpp chain; 1 elem/lane. MFMA issue floor ~640
// cyc/SIMD/step (fill-4 invariant).

#define T_LEN 2048
#define IN_DIM 16
#define CHUNK 32
#define NROWS 4

typedef __attribute__((ext_vector_type(4))) float f32x4;
typedef __attribute__((ext_vector_type(8))) short s16x8;

__device__ __forceinline__ short f2bf(float f) {
    union { float f; unsigned u; } v; v.f = f;
    unsigned r = v.u + 0x7fffu + ((v.u >> 16) & 1u);   // RNE
    return (short)(r >> 16);
}
__device__ __forceinline__ unsigned pk_bf16(float a, float b) {
#if __has_builtin(__builtin_amdgcn_cvt_pk_bf16_f32)
    typedef __attribute__((ext_vector_type(2))) __bf16 bf16x2;
    bf16x2 r = __builtin_amdgcn_cvt_pk_bf16_f32(a, b);
    union { bf16x2 v; unsigned u; } c; c.v = r;
    return c.u;
#else
    return (unsigned)(unsigned short)f2bf(a) | ((unsigned)(unsigned short)f2bf(b) << 16);
#endif
}
// merge quarter-dense regs: lanes 0-3 keep r0; 4-7 <- r1[0-3]; 8-11 <- r2[0-3];
// 12-15 <- r3[0-3].  row_ror:n pulls from lane (i-n) mod 16 (verified R10).
__device__ __forceinline__ float pack4(float r0, float r1, float r2, float r3) {
    int d = __float_as_int(r0);
    d = __builtin_amdgcn_update_dpp(d, __float_as_int(r1), 0x124, 0xF, 0x2, false);
    d = __builtin_amdgcn_update_dpp(d, __float_as_int(r2), 0x128, 0xF, 0x4, false);
    d = __builtin_amdgcn_update_dpp(d, __float_as_int(r3), 0x12C, 0xF, 0x8, false);
    return __int_as_float(d);
}

__global__ __launch_bounds__(512, 2)
void slstm_persistent(const float* __restrict__ x,
                      const float* __restrict__ W_ih,
                      const float* __restrict__ W_hh,
                      const float* __restrict__ b_ih,
                      const float* __restrict__ b_hh,
                      const float* __restrict__ fc_w,
                      const float* __restrict__ fc_b,
                      float* __restrict__ out)
{
    // h: element (col, nb) at shorts[(col>>5)*128 + ((col>>3)&3)*32 + nb*8 + (col&7)]
    // = frag-ordered for the B-operand; the 16 valid reader lanes span all 32
    // banks exactly twice -> conflict-free. 1 KB/buf.
    __shared__ __align__(16) unsigned short h_frag[2][512];
    // x frags [buf][slot][qh 2][n 4][j 8] bf16, dbuf (8 KB)
    __shared__ __align__(16) unsigned short xlds[2][CHUNK][2][4][8];
    __shared__ float red[NROWS];

    const int tid  = threadIdx.x;
    const int lane = tid & 63;
    const int wv   = tid >> 6;          // wave 0..7 = col-group
    const int c16  = lane & 15;
    const int quad = lane >> 4;         // 0..3
    const int b0   = blockIdx.x * NROWS;

    const float kNL2E = -1.44269504f;

    // ---- weights pre-scaled; wave owns col-group wv x 4 gates ----
    s16x8 wfrag[4][5];                  // [g][kf], kf4 = x
    f32x4 biasC[4];
    #pragma unroll
    for (int g = 0; g < 4; ++g) {
        const float scale = (g == 2) ? (2.0f * kNL2E) : kNL2E;
        const int n = g * 128 + wv * 16 + c16;
        #pragma unroll
        for (int kf = 0; kf < 5; ++kf) {
            s16x8 fr;
            #pragma unroll
            for (int j = 0; j < 8; ++j) {
                const int k = kf * 32 + quad * 8 + j;
                float v;
                if (kf < 4) v = W_hh[n * 128 + k];
                else {
                    const int kk = k - 128;
                    v = (kk < IN_DIM) ? W_ih[n * IN_DIM + kk] : 0.0f;
                }
                fr[j] = f2bf(v * scale);
            }
            wfrag[g][kf] = fr;
        }
        #pragma unroll
        for (int r = 0; r < 4; ++r) {
            const int m = g * 128 + wv * 16 + quad * 4 + r;
            biasC[g][r] = (b_ih[m] + b_hh[m]) * scale;
        }
    }

    // zero h buf 0 (h0 = 0); buf 1 fully written at t=0 before first read
    if (tid < 256) ((unsigned*)h_frag)[tid] = 0;

    // ---- packed-lane identity: element (col, nb) ----
    const int e    = c16 >> 2;
    const int nb   = c16 & 3;
    const int col  = wv * 16 + quad * 4 + e;
    const int waddr = (col >> 5) * 128 + ((col >> 3) & 3) * 32 + nb * 8 + (col & 7);
    // h read: valid lanes c16<4 read 16B at v*16 (v = quad*4+c16); others addr 0
    const int hoff = (c16 < 4) ? ((quad * 4 + c16) * 16) : 0;   // bytes within frag
    // x read: valid lanes quad<2 && c16<4
    const bool xv = (quad < 2) && (c16 < 4);
    const int xoff  = xv ? (quad * 64 + c16 * 16) : 0;          // bytes
    const int xmask = xv ? ~0 : 0;

    float c_st = 0.0f, h_ep = 0.0f;

    // ---- prologue: stage chunk 0 -> xlds[0]; chunk 1 -> xreg ----
    f32x4 xreg;
    {
        const int flat4 = tid * 4;
        const int b_loc = flat4 >> 9;
        const int rem   = flat4 & 511;
        const float* xr = x + (size_t)(b0 + b_loc) * (T_LEN * IN_DIM);
        f32x4 v4 = *(const f32x4*)(xr + rem);
        const int slot = rem >> 4, feat = rem & 15;
        unsigned* dst = (unsigned*)&xlds[0][slot][feat >> 3][b_loc][feat & 7];
        dst[0] = pk_bf16(v4[0], v4[1]);
        dst[1] = pk_bf16(v4[2], v4[3]);
        xreg = *(const f32x4*)(xr + CHUNK * IN_DIM + rem);
    }
    __syncthreads();

    // acc ping-pong buffers; accA = bias + x-MFMA for t=0
    f32x4 accA[4], accB[4];
    {
        s16x8 zx0 = *(const s16x8*)((const char*)xlds + (xoff & xmask));
        #pragma unroll
        for (int g = 0; g < 4; ++g)
            accA[g] = __builtin_amdgcn_mfma_f32_16x16x32_bf16(wfrag[g][4], zx0, biasC[g], 0, 0, 0);
    }

    // incremental x-frag byte offset for step ts=t+1 (walks 2x4KB dbuf)
    int off_cur = 128 + xoff;

    // step: R12 phase schedule, in-place chains on aci, refresh into aco
    auto step_impl = [&](const int RB, const int WB, f32x4 (&aci)[4], f32x4 (&aco)[4]) {
        const char* hb = (const char*)h_frag[RB];
        s16x8 zf[4];
        #pragma unroll
        for (int kf = 0; kf < 4; ++kf)
            zf[kf] = *(const s16x8*)(hb + hoff + kf * 256);
        // x frag for t+1 (independent of h(t)) — load early
        s16x8 zxn = *(const s16x8*)((const char*)xlds + (off_cur & xmask));
        off_cur = (off_cur + 128) & 8191;

        // ---- P1: g,i,f chains interleaved (12 MFMA — pure matrix phase) ----
        #pragma unroll
        for (int kf = 0; kf < 4; ++kf) {
            aci[2] = __builtin_amdgcn_mfma_f32_16x16x32_bf16(wfrag[2][kf], zf[kf], aci[2], 0, 0, 0);
            aci[0] = __builtin_amdgcn_mfma_f32_16x16x32_bf16(wfrag[0][kf], zf[kf], aci[0], 0, 0, 0);
            aci[1] = __builtin_amdgcn_mfma_f32_16x16x32_bf16(wfrag[1][kf], zf[kf], aci[1], 0, 0, 0);
        }
        __builtin_amdgcn_sched_barrier(0);

        // ---- P2: o-chain (4 dep MFMA) || packs+exp2 of g,i,f,o + c-numerator ----
        aci[3] = __builtin_amdgcn_mfma_f32_16x16x32_bf16(wfrag[3][0], zf[0], aci[3], 0, 0, 0);
        aci[3] = __builtin_amdgcn_mfma_f32_16x16x32_bf16(wfrag[3][1], zf[1], aci[3], 0, 0, 0);
        aci[3] = __builtin_amdgcn_mfma_f32_16x16x32_bf16(wfrag[3][2], zf[2], aci[3], 0, 0, 0);
        aci[3] = __builtin_amdgcn_mfma_f32_16x16x32_bf16(wfrag[3][3], zf[3], aci[3], 0, 0, 0);
        const float dg = pack4(aci[2][0], aci[2][1], aci[2][2], aci[2][3]);
        const float eg = __builtin_amdgcn_exp2f(dg);
        const float di = pack4(aci[0][0], aci[0][1], aci[0][2], aci[0][3]);
        const float ei = __builtin_amdgcn_exp2f(di);
        const float df = pack4(aci[1][0], aci[1][1], aci[1][2], aci[1][3]);
        const float ef = __builtin_amdgcn_exp2f(df);
        const float af  = 1.0f + ef;
        const float t1  = (1.0f + ei) * (1.0f + eg);
        const float num = fmaf(c_st, t1, (1.0f - eg) * af);
        const float den = af * t1;
        // o-gate hoisted off the post-ec serial path
        const float dojj = pack4(aci[3][0], aci[3][1], aci[3][2], aci[3][3]);
        const float eo  = __builtin_amdgcn_exp2f(dojj);
        const float p_o = 1.0f + eo;
        // pin the interleave: 1 MFMA : 6 VALU, x4 — o-chain dep-stall cycles
        // become VALU issue slots (benched structure from R12)
        #pragma unroll
        for (int kq = 0; kq < 4; ++kq) {
            __builtin_amdgcn_sched_group_barrier(0x008, 1, 0);  // 1 MFMA
            __builtin_amdgcn_sched_group_barrier(0x002, 6, 0);  // 6 VALU
        }
        __builtin_amdgcn_sched_barrier(0);

        // ---- P3: serial tail covered by acc refresh (independent MFMAs) ----
        aco[0] = __builtin_amdgcn_mfma_f32_16x16x32_bf16(wfrag[0][4], zxn, biasC[0], 0, 0, 0);
        aco[1] = __builtin_amdgcn_mfma_f32_16x16x32_bf16(wfrag[1][4], zxn, biasC[1], 0, 0, 0);
        const float cn = num * __builtin_amdgcn_rcpf(den);
        c_st = cn;
        const float ec = __builtin_amdgcn_exp2f(fminf(cn * (2.0f * kNL2E), 40.f));
        const float hn = (1.0f - ec) * __builtin_amdgcn_rcpf(p_o * (1.0f + ec));
        h_ep = hn;
        h_frag[WB][waddr] = (unsigned short)pk_bf16(hn, hn);   // 1 cvt + ds_write_b16
        // last two refresh MFMAs drain across the barrier into the next
        // step's zf-read latency window
        aco[2] = __builtin_amdgcn_mfma_f32_16x16x32_bf16(wfrag[2][4], zxn, biasC[2], 0, 0, 0);
        aco[3] = __builtin_amdgcn_mfma_f32_16x16x32_bf16(wfrag[3][4], zxn, biasC[3], 0, 0, 0);
        __syncthreads();
    };

    for (int t = 0; t < T_LEN; t += 2) {
        step_impl(0, 1, accA, accB);

        // ---- spread x maintenance ----
        const int iter  = (t >> 1) & 15;
        const int cbase = t & ~(CHUNK - 1);
        if (iter < 2) {
            if (cbase + CHUNK < T_LEN) {
                const int flat4 = tid * 4;
                const int b_loc = flat4 >> 9;
                const int rem   = flat4 & 511;
                const int slot = rem >> 4, feat = rem & 15;
                const int nb1 = ((cbase >> 5) + 1) & 1;
                unsigned* dst = (unsigned*)&xlds[nb1][slot][feat >> 3][b_loc][(feat & 7) + 2 * iter];
                dst[0] = pk_bf16(xreg[2 * iter], xreg[2 * iter + 1]);
            }
        } else if (iter == 8) {
            const int tnext = cbase + 2 * CHUNK;
            if (tnext < T_LEN) {
                const int flat4 = tid * 4;
                const int b_loc = flat4 >> 9;
                const int rem   = flat4 & 511;
                xreg = *(const f32x4*)(x + (size_t)(b0 + b_loc) * (T_LEN * IN_DIM)
                                         + (size_t)tnext * IN_DIM + rem);
            }
        }

        step_impl(1, 0, accB, accA);
    }

    // ---- epilogue: out[b] = sum_cols h * fc_w + fc_b ----
    float v = h_ep * fc_w[col];
    v += __shfl_xor(v, 4);
    v += __shfl_xor(v, 8);
    v += __shfl_xor(v, 16);
    v += __shfl_xor(v, 32);
    if (tid < NROWS) red[tid] = 0.0f;
    __syncthreads();
    if (lane < NROWS) atomicAdd(&red[nb], v);
    __syncthreads();
    if (tid < NROWS) out[b0 + tid] = red[tid] + fc_b[0];
}

extern "C" void kernel_launch(void* const* d_in, const int* in_sizes, int n_in,
                              void* d_out, int out_size, void* d_ws, size_t ws_size,
                              hipStream_t stream) {
    const float* x    = (const float*)d_in[0];
    const float* W_ih = (const float*)d_in[1];
    const float* W_hh = (const float*)d_in[2];
    const float* b_ih = (const float*)d_in[3];
    const float* b_hh = (const float*)d_in[4];
    const float* fc_w = (const float*)d_in[5];
    const float* fc_b = (const float*)d_in[6];
    float* out = (float*)d_out;

    slstm_persistent<<<256, 512, 0, stream>>>(x, W_ih, W_hh, b_ih, b_hh, fc_w, fc_b, out);
}

// Round 4
// 1057.625 us; speedup vs baseline: 1.2317x; 1.1436x over previous
//
#include <hip/hip_runtime.h>
#include <hip/hip_bf16.h>
#include <type_traits>

// SLSTM recurrence + Linear.  B=1024, T=2048, IN=16, H=128, OUT=1.
// R15 = R12-structure + quad-batched x-projection at N-fill 16:
//   x-gate MFMAs drop 4/step -> 4/quad (one N=16 MFMA per gate covering 4
//   timesteps x 4 batch rows).  Per-SIMD MFMA/step: 40 -> 34 (-116 cyc of
//   the 776-cyc matrix floor that MfmaUtil=50% says we pay every step).
// Mechanics (no lane rotation needed!):
//   - acc column c = 4*ts_phase + nb.  Phase p consumes cols 4p..4p+3.
//   - h-frag LDS layout UNCHANGED (indexed by (k, nb)); what rotates is the
//     READER window: at phase p only lanes c16 in [4p,4p+3] read real h
//     (hoff -> buffer (p-1)&3); all other lanes read a permanently-zero
//     buffer, so A*0 = 0 preserves other phases' acc columns bit-exactly.
//   - 4+1 h buffers: buffer p written at phase p (cols consumed at p+1),
//     buffer 4 never written (the zero source).  1 KB each.
//   - extraction pack4p<P>: same 3-dpp chain, bank masks rotated by P.
//   - reseed for next quad: gate g's x-MFMA at phase g (accA/accB ping-pong,
//     unrolled x8 phases) -> every phase's serial tail keeps 1 independent
//     MFMA of cover, same role as R12's accN refresh.
// R13/R14 lessons kept: no chain-flattening (no stalls at 2 waves/SIMD),
// cvt_pk h-write, o-gate hoisted off the post-ec serial path.
// Structure: 256 WGs x 512 thr (8 waves = 2/SIMD), 4 batch rows/WG, all 256
// CUs, zero cross-CU traffic. Wave owns col-group wv x 4 gates; 1 elem/lane.

#define T_LEN 2048
#define IN_DIM 16
#define CHUNK 32
#define NROWS 4

typedef __attribute__((ext_vector_type(4))) float f32x4;
typedef __attribute__((ext_vector_type(8))) short s16x8;

__device__ __forceinline__ short f2bf(float f) {
    union { float f; unsigned u; } v; v.f = f;
    unsigned r = v.u + 0x7fffu + ((v.u >> 16) & 1u);   // RNE
    return (short)(r >> 16);
}
__device__ __forceinline__ unsigned pk_bf16(float a, float b) {
#if __has_builtin(__builtin_amdgcn_cvt_pk_bf16_f32)
    typedef __attribute__((ext_vector_type(2))) __bf16 bf16x2;
    bf16x2 r = __builtin_amdgcn_cvt_pk_bf16_f32(a, b);
    union { bf16x2 v; unsigned u; } c; c.v = r;
    return c.u;
#else
    return (unsigned)(unsigned short)f2bf(a) | ((unsigned)(unsigned short)f2bf(b) << 16);
#endif
}
// Phase-P pack: lane group e (lanes 4e..4e+3 of each 16-row) takes acc reg e
// from source lane 4P+nb via row_ror:4((e-P)&3).  Shift amounts are fixed
// (4,8,12); only the bank masks rotate with P.  P=0 == verified R10 pack4.
template<int P>
__device__ __forceinline__ float pack4p(const f32x4& a) {
    int d = __float_as_int(a[P]);
    d = __builtin_amdgcn_update_dpp(d, __float_as_int(a[(P + 1) & 3]), 0x124, 0xF, 1 << ((P + 1) & 3), false);
    d = __builtin_amdgcn_update_dpp(d, __float_as_int(a[(P + 2) & 3]), 0x128, 0xF, 1 << ((P + 2) & 3), false);
    d = __builtin_amdgcn_update_dpp(d, __float_as_int(a[(P + 3) & 3]), 0x12C, 0xF, 1 << ((P + 3) & 3), false);
    return __int_as_float(d);
}

__global__ __launch_bounds__(512, 2)
void slstm_persistent(const float* __restrict__ x,
                      const float* __restrict__ W_ih,
                      const float* __restrict__ W_hh,
                      const float* __restrict__ b_ih,
                      const float* __restrict__ b_hh,
                      const float* __restrict__ fc_w,
                      const float* __restrict__ fc_b,
                      float* __restrict__ out)
{
    // h: 5 buffers x [kf 4][chunk 16][8 shorts]; element (k=col, nb) at
    // shorts[(k>>5)*128 + ((k>>3)&3)*32 + nb*8 + (k&7)].  Buffer p written at
    // phase p; buffer 4 permanently zero (read by out-of-window lanes).
    __shared__ __align__(16) unsigned short h_frag[5][512];
    // x quad-frags: [buf 2][quadslot 8][512 shorts]; B[k][c=4s+nb] chunk
    // layout: 16B chunk index = (k>>3)*16 + c  (reader lane reads lane*16).
    // k>=16 halves permanently zero (IN_DIM=16; also W_ih frag zeros k>=16).
    __shared__ __align__(16) unsigned short xq[8192];     // 16 KB
    __shared__ float red[NROWS];

    const int tid  = threadIdx.x;
    const int lane = tid & 63;
    const int wv   = tid >> 6;          // wave 0..7 = col-group
    const int c16  = lane & 15;
    const int quad = lane >> 4;         // 0..3
    const int b0   = blockIdx.x * NROWS;

    const float kNL2E = -1.44269504f;

    // ---- weights pre-scaled; wave owns col-group wv x 4 gates ----
    s16x8 wfrag[4][5];                  // [g][kf], kf4 = x (k>=IN_DIM zeroed)
    f32x4 biasC[4];
    #pragma unroll
    for (int g = 0; g < 4; ++g) {
        const float scale = (g == 2) ? (2.0f * kNL2E) : kNL2E;
        const int n = g * 128 + wv * 16 + c16;
        #pragma unroll
        for (int kf = 0; kf < 5; ++kf) {
            s16x8 fr;
            #pragma unroll
            for (int j = 0; j < 8; ++j) {
                const int k = kf * 32 + quad * 8 + j;
                float v;
                if (kf < 4) v = W_hh[n * 128 + k];
                else {
                    const int kk = k - 128;
                    v = (kk < IN_DIM) ? W_ih[n * IN_DIM + kk] : 0.0f;
                }
                fr[j] = f2bf(v * scale);
            }
            wfrag[g][kf] = fr;
        }
        #pragma unroll
        for (int r = 0; r < 4; ++r) {
            const int m = g * 128 + wv * 16 + quad * 4 + r;
            biasC[g][r] = (b_ih[m] + b_hh[m]) * scale;
        }
    }

    // ---- zero h buffers (incl. zero-source buf 4) and xq (k>=16 holes) ----
    {
        unsigned* hz = (unsigned*)h_frag;      // 1280 unsigneds (5120 B)
        hz[tid] = 0; hz[tid + 512] = 0;
        if (tid < 256) hz[tid + 1024] = 0;
        unsigned* xz = (unsigned*)xq;          // 4096 unsigneds (16 KB)
        #pragma unroll
        for (int i = 0; i < 8; ++i) xz[tid + i * 512] = 0;
    }
    __syncthreads();

    // ---- packed-lane identity: element (col, nb) — fixed across phases ----
    const int e    = c16 >> 2;
    const int nb   = c16 & 3;
    const int col  = wv * 16 + quad * 4 + e;
    const int waddr = (col >> 5) * 128 + ((col >> 3) & 3) * 32 + nb * 8 + (col & 7);
    // per-phase h read offset (bytes into h_frag): window lanes -> buffer
    // (q+3)&3, others -> zero buffer 4; chunk = quad*4 + (c16&3) either way.
    int hoffP[4];
    #pragma unroll
    for (int q = 0; q < 4; ++q)
        hoffP[q] = (((c16 >> 2) == q) ? ((q + 3) & 3) : 4) * 1024
                 + (quad * 4 + (c16 & 3)) * 16;

    float c_st = 0.0f, h_ep = 0.0f;

    // ---- prologue: stage chunk 0 -> xq buf0 (quad layout); chunk1 -> xreg ----
    f32x4 xreg;
    {
        const int flat4 = tid * 4;
        const int b_loc = flat4 >> 9;
        const int rem   = flat4 & 511;
        const float* xr = x + (size_t)(b0 + b_loc) * (T_LEN * IN_DIM);
        f32x4 v4 = *(const f32x4*)(xr + rem);
        const int slot = rem >> 4, f = rem & 15;      // ts-in-chunk, feat base
        const int qs = slot >> 2, s = slot & 3;
        unsigned* dst = (unsigned*)&xq[qs * 512 + (f >> 3) * 128 + (4 * s + b_loc) * 8 + (f & 7)];
        dst[0] = pk_bf16(v4[0], v4[1]);
        dst[1] = pk_bf16(v4[2], v4[3]);
        xreg = *(const f32x4*)(xr + CHUNK * IN_DIM + rem);
    }
    __syncthreads();

    // ---- seed quad 0: zx4 for quads walks 1 KB per quad through 16 KB ----
    const char* xb = (const char*)xq;
    s16x8 zx4r = *(const s16x8*)(xb + lane * 16);           // quad 0
    f32x4 accA[4], accB[4];
    #pragma unroll
    for (int g = 0; g < 4; ++g)
        accA[g] = __builtin_amdgcn_mfma_f32_16x16x32_bf16(wfrag[g][4], zx4r, biasC[g], 0, 0, 0);
    zx4r = *(const s16x8*)(xb + 1024 + lane * 16);          // quad 1
    int xqoff = 2 * 1024 + lane * 16;                       // next prefetch: quad 2

    const char* hb = (const char*)h_frag;
    unsigned short* hw = (unsigned short*)h_frag;

    // one phase = one timestep.  acc: current quad's gates; accn: next quad's
    // seeds (gate P reseeded at phase P).
    auto phaseF = [&](auto Pc, f32x4 (&acc)[4], f32x4 (&accn)[4]) {
        constexpr int P = decltype(Pc)::value;
        s16x8 zf[4];
        #pragma unroll
        for (int kf = 0; kf < 4; ++kf)
            zf[kf] = *(const s16x8*)(hb + hoffP[P] + kf * 256);

        // ---- P1: g,i,f chains interleaved (12 MFMA — pure matrix phase) ----
        #pragma unroll
        for (int kf = 0; kf < 4; ++kf) {
            acc[2] = __builtin_amdgcn_mfma_f32_16x16x32_bf16(wfrag[2][kf], zf[kf], acc[2], 0, 0, 0);
            acc[0] = __builtin_amdgcn_mfma_f32_16x16x32_bf16(wfrag[0][kf], zf[kf], acc[0], 0, 0, 0);
            acc[1] = __builtin_amdgcn_mfma_f32_16x16x32_bf16(wfrag[1][kf], zf[kf], acc[1], 0, 0, 0);
        }
        __builtin_amdgcn_sched_barrier(0);

        // ---- P2: o-chain (4 dep MFMA) || packs+exp2 + c-numerator ----
        acc[3] = __builtin_amdgcn_mfma_f32_16x16x32_bf16(wfrag[3][0], zf[0], acc[3], 0, 0, 0);
        acc[3] = __builtin_amdgcn_mfma_f32_16x16x32_bf16(wfrag[3][1], zf[1], acc[3], 0, 0, 0);
        acc[3] = __builtin_amdgcn_mfma_f32_16x16x32_bf16(wfrag[3][2], zf[2], acc[3], 0, 0, 0);
        acc[3] = __builtin_amdgcn_mfma_f32_16x16x32_bf16(wfrag[3][3], zf[3], acc[3], 0, 0, 0);
        const float dg = pack4p<P>(acc[2]);
        const float eg = __builtin_amdgcn_exp2f(dg);
        const float di = pack4p<P>(acc[0]);
        const float ei = __builtin_amdgcn_exp2f(di);
        const float df = pack4p<P>(acc[1]);
        const float ef = __builtin_amdgcn_exp2f(df);
        const float af  = 1.0f + ef;
        const float t1  = (1.0f + ei) * (1.0f + eg);
        const float num = fmaf(c_st, t1, (1.0f - eg) * af);
        const float den = af * t1;
        const float dojj = pack4p<P>(acc[3]);
        const float eo  = __builtin_amdgcn_exp2f(dojj);
        const float p_o = 1.0f + eo;
        #pragma unroll
        for (int kq = 0; kq < 4; ++kq) {
            __builtin_amdgcn_sched_group_barrier(0x008, 1, 0);  // 1 MFMA
            __builtin_amdgcn_sched_group_barrier(0x002, 6, 0);  // 6 VALU
        }
        __builtin_amdgcn_sched_barrier(0);

        // ---- P3: serial tail covered by next-quad gate-P reseed MFMA ----
        accn[P] = __builtin_amdgcn_mfma_f32_16x16x32_bf16(wfrag[P][4], zx4r, biasC[P], 0, 0, 0);
        const float cn = num * __builtin_amdgcn_rcpf(den);
        c_st = cn;
        const float ec = __builtin_amdgcn_exp2f(fminf(cn * (2.0f * kNL2E), 40.f));
        const float hn = (1.0f - ec) * __builtin_amdgcn_rcpf(p_o * (1.0f + ec));
        h_ep = hn;
        hw[P * 512 + waddr] = (unsigned short)pk_bf16(hn, hn);
        if constexpr (P == 3) {
            // prefetch zx4 for quad Q+2 (consumed by next quad's reseeds)
            zx4r = *(const s16x8*)(xb + xqoff);
            xqoff = (xqoff + 1024) & 16383;
        }
        __syncthreads();
    };

    auto maint = [&](int Q) {
        const int qi = Q & 7;
        const int chunkI = Q >> 3;
        if (qi < 2) {
            if (chunkI < (T_LEN / CHUNK) - 1) {
                const int flat4 = tid * 4;
                const int b_loc = flat4 >> 9;
                const int rem   = flat4 & 511;
                const int slot = rem >> 4, f = rem & 15;
                const int qs = slot >> 2, s = slot & 3;
                const int nb1 = (chunkI + 1) & 1;
                const int k0 = f + 2 * qi;
                unsigned* dst = (unsigned*)&xq[nb1 * 4096 + qs * 512 + (k0 >> 3) * 128 + (4 * s + b_loc) * 8 + (k0 & 7)];
                dst[0] = pk_bf16(xreg[2 * qi], xreg[2 * qi + 1]);
            }
        } else if (qi == 4) {
            const int tnext = (chunkI + 2) * CHUNK;
            if (tnext < T_LEN) {
                const int flat4 = tid * 4;
                const int b_loc = flat4 >> 9;
                const int rem   = flat4 & 511;
                xreg = *(const f32x4*)(x + (size_t)(b0 + b_loc) * (T_LEN * IN_DIM)
                                         + (size_t)tnext * IN_DIM + rem);
            }
        }
    };

    for (int Q = 0; Q < T_LEN / 4; Q += 2) {
        phaseF(std::integral_constant<int, 0>{}, accA, accB);
        maint(Q);
        phaseF(std::integral_constant<int, 1>{}, accA, accB);
        phaseF(std::integral_constant<int, 2>{}, accA, accB);
        phaseF(std::integral_constant<int, 3>{}, accA, accB);
        phaseF(std::integral_constant<int, 0>{}, accB, accA);
        maint(Q + 1);
        phaseF(std::integral_constant<int, 1>{}, accB, accA);
        phaseF(std::integral_constant<int, 2>{}, accB, accA);
        phaseF(std::integral_constant<int, 3>{}, accB, accA);
    }

    // ---- epilogue: out[b] = sum_cols h * fc_w + fc_b ----
    float v = h_ep * fc_w[col];
    v += __shfl_xor(v, 4);
    v += __shfl_xor(v, 8);
    v += __shfl_xor(v, 16);
    v += __shfl_xor(v, 32);
    if (tid < NROWS) red[tid] = 0.0f;
    __syncthreads();
    if (lane < NROWS) atomicAdd(&red[nb], v);
    __syncthreads();
    if (tid < NROWS) out[b0 + tid] = red[tid] + fc_b[0];
}

extern "C" void kernel_launch(void* const* d_in, const int* in_sizes, int n_in,
                              void* d_out, int out_size, void* d_ws, size_t ws_size,
                              hipStream_t stream) {
    const float* x    = (const float*)d_in[0];
    const float* W_ih = (const float*)d_in[1];
    const float* W_hh = (const float*)d_in[2];
    const float* b_ih = (const float*)d_in[3];
    const float* b_hh = (const float*)d_in[4];
    const float* fc_w = (const float*)d_in[5];
    const float* fc_b = (const float*)d_in[6];
    float* out = (float*)d_out;

    slstm_persistent<<<256, 512, 0, stream>>>(x, W_ih, W_hh, b_ih, b_hh, fc_w, fc_b, out);
}

// Round 5
// 1034.112 us; speedup vs baseline: 1.2597x; 1.0227x over previous
//
#include <hip/hip_runtime.h>
#include <hip/hip_bf16.h>
#include <type_traits>

// SLSTM recurrence + Linear.  B=1024, T=2048, IN=16, H=128, OUT=1.
// R16 = R15 + zf bank-conflict fix:
//   R15's out-of-window lanes read the zero buffer at per-lane chunk offsets
//   -> 32 distinct 16B requests per ds_read_b128 covering the same 256B bank
//   stripe twice each = 4-way conflict = +124 cyc/step/CU (measured: conflict
//   counter 5.7M -> 70.8M, delta/256CU/2048steps = 124).  Fix: out-of-window
//   lanes read ONE uniform address (buf4 base + kf*256) -> broadcast request,
//   like R12's addr-0 trick.  Window lanes unchanged (2-way = free).
// R15 recap (benched 1047us steady, -15%):
//   Quad-batched x-projection at N-fill 16: one x-MFMA per gate per 4
//   timesteps; per-SIMD MFMA/step 40 -> 34.  Phase p consumes acc cols
//   4p..4p+3; h-frag reader window rotates (window lanes -> buffer (p-1)&3,
//   others -> zero buffer 4; A*0=0 preserves other phases' acc cols).
//   pack4p<P>: 3-dpp chain, bank masks rotated by P.  Reseed gate g at
//   phase g (accA/accB ping-pong) covers each phase's serial tail.
// R13/R14 lessons: no chain-flattening (no stalls at 2 waves/SIMD), cvt_pk
// h-write, o-gate hoisted off the post-ec serial path.
// Structure: 256 WGs x 512 thr (8 waves = 2/SIMD), 4 batch rows/WG, all 256
// CUs, zero cross-CU traffic. Wave owns col-group wv x 4 gates; 1 elem/lane.
// Budget (R15 counters): step 1227 cyc/SIMD = MFMA busy 606 (34 MFMA, ~pipe-
// saturated: ~19 cyc/SIMD each) + VALU 583 + conflicts 124, ~fully additive.

#define T_LEN 2048
#define IN_DIM 16
#define CHUNK 32
#define NROWS 4

typedef __attribute__((ext_vector_type(4))) float f32x4;
typedef __attribute__((ext_vector_type(8))) short s16x8;

__device__ __forceinline__ short f2bf(float f) {
    union { float f; unsigned u; } v; v.f = f;
    unsigned r = v.u + 0x7fffu + ((v.u >> 16) & 1u);   // RNE
    return (short)(r >> 16);
}
__device__ __forceinline__ unsigned pk_bf16(float a, float b) {
#if __has_builtin(__builtin_amdgcn_cvt_pk_bf16_f32)
    typedef __attribute__((ext_vector_type(2))) __bf16 bf16x2;
    bf16x2 r = __builtin_amdgcn_cvt_pk_bf16_f32(a, b);
    union { bf16x2 v; unsigned u; } c; c.v = r;
    return c.u;
#else
    return (unsigned)(unsigned short)f2bf(a) | ((unsigned)(unsigned short)f2bf(b) << 16);
#endif
}
// Phase-P pack: lane group e (lanes 4e..4e+3 of each 16-row) takes acc reg e
// from source lane 4P+nb via row_ror:4((e-P)&3).  Shift amounts are fixed
// (4,8,12); only the bank masks rotate with P.  P=0 == verified R10 pack4.
template<int P>
__device__ __forceinline__ float pack4p(const f32x4& a) {
    int d = __float_as_int(a[P]);
    d = __builtin_amdgcn_update_dpp(d, __float_as_int(a[(P + 1) & 3]), 0x124, 0xF, 1 << ((P + 1) & 3), false);
    d = __builtin_amdgcn_update_dpp(d, __float_as_int(a[(P + 2) & 3]), 0x128, 0xF, 1 << ((P + 2) & 3), false);
    d = __builtin_amdgcn_update_dpp(d, __float_as_int(a[(P + 3) & 3]), 0x12C, 0xF, 1 << ((P + 3) & 3), false);
    return __int_as_float(d);
}

__global__ __launch_bounds__(512, 2)
void slstm_persistent(const float* __restrict__ x,
                      const float* __restrict__ W_ih,
                      const float* __restrict__ W_hh,
                      const float* __restrict__ b_ih,
                      const float* __restrict__ b_hh,
                      const float* __restrict__ fc_w,
                      const float* __restrict__ fc_b,
                      float* __restrict__ out)
{
    // h: 5 buffers x [kf 4][chunk 16][8 shorts]; element (k=col, nb) at
    // shorts[(k>>5)*128 + ((k>>3)&3)*32 + nb*8 + (k&7)].  Buffer p written at
    // phase p; buffer 4 permanently zero (read broadcast by non-window lanes).
    __shared__ __align__(16) unsigned short h_frag[5][512];
    // x quad-frags: [buf 2][quadslot 8][512 shorts]; B[k][c=4s+nb] chunk
    // layout: 16B chunk index = (k>>3)*16 + c  (reader lane reads lane*16).
    // k>=16 halves permanently zero (IN_DIM=16; also W_ih frag zeros k>=16).
    __shared__ __align__(16) unsigned short xq[8192];     // 16 KB
    __shared__ float red[NROWS];

    const int tid  = threadIdx.x;
    const int lane = tid & 63;
    const int wv   = tid >> 6;          // wave 0..7 = col-group
    const int c16  = lane & 15;
    const int quad = lane >> 4;         // 0..3
    const int b0   = blockIdx.x * NROWS;

    const float kNL2E = -1.44269504f;

    // ---- weights pre-scaled; wave owns col-group wv x 4 gates ----
    s16x8 wfrag[4][5];                  // [g][kf], kf4 = x (k>=IN_DIM zeroed)
    f32x4 biasC[4];
    #pragma unroll
    for (int g = 0; g < 4; ++g) {
        const float scale = (g == 2) ? (2.0f * kNL2E) : kNL2E;
        const int n = g * 128 + wv * 16 + c16;
        #pragma unroll
        for (int kf = 0; kf < 5; ++kf) {
            s16x8 fr;
            #pragma unroll
            for (int j = 0; j < 8; ++j) {
                const int k = kf * 32 + quad * 8 + j;
                float v;
                if (kf < 4) v = W_hh[n * 128 + k];
                else {
                    const int kk = k - 128;
                    v = (kk < IN_DIM) ? W_ih[n * IN_DIM + kk] : 0.0f;
                }
                fr[j] = f2bf(v * scale);
            }
            wfrag[g][kf] = fr;
        }
        #pragma unroll
        for (int r = 0; r < 4; ++r) {
            const int m = g * 128 + wv * 16 + quad * 4 + r;
            biasC[g][r] = (b_ih[m] + b_hh[m]) * scale;
        }
    }

    // ---- zero h buffers (incl. zero-source buf 4) and xq (k>=16 holes) ----
    {
        unsigned* hz = (unsigned*)h_frag;      // 1280 unsigneds (5120 B)
        hz[tid] = 0; hz[tid + 512] = 0;
        if (tid < 256) hz[tid + 1024] = 0;
        unsigned* xz = (unsigned*)xq;          // 4096 unsigneds (16 KB)
        #pragma unroll
        for (int i = 0; i < 8; ++i) xz[tid + i * 512] = 0;
    }
    __syncthreads();

    // ---- packed-lane identity: element (col, nb) — fixed across phases ----
    const int e    = c16 >> 2;
    const int nb   = c16 & 3;
    const int col  = wv * 16 + quad * 4 + e;
    const int waddr = (col >> 5) * 128 + ((col >> 3) & 3) * 32 + nb * 8 + (col & 7);
    // per-phase h read offset (bytes into h_frag): window lanes (c16>>2 == p)
    // read buffer (p+3)&3 at chunk quad*4 + (c16&3); ALL other lanes read the
    // SAME address (zero buf 4, offset 0) -> one broadcast request per
    // ds_read_b128 instead of 16 distinct stripe addresses (the R15 4-way
    // conflict, measured +124 cyc/step/CU).
    int hoffP[4];
    #pragma unroll
    for (int q = 0; q < 4; ++q)
        hoffP[q] = ((c16 >> 2) == q)
                 ? ((q + 3) & 3) * 1024 + (quad * 4 + (c16 & 3)) * 16
                 : 4 * 1024;

    float c_st = 0.0f, h_ep = 0.0f;

    // ---- prologue: stage chunk 0 -> xq buf0 (quad layout); chunk1 -> xreg ----
    f32x4 xreg;
    {
        const int flat4 = tid * 4;
        const int b_loc = flat4 >> 9;
        const int rem   = flat4 & 511;
        const float* xr = x + (size_t)(b0 + b_loc) * (T_LEN * IN_DIM);
        f32x4 v4 = *(const f32x4*)(xr + rem);
        const int slot = rem >> 4, f = rem & 15;      // ts-in-chunk, feat base
        const int qs = slot >> 2, s = slot & 3;
        unsigned* dst = (unsigned*)&xq[qs * 512 + (f >> 3) * 128 + (4 * s + b_loc) * 8 + (f & 7)];
        dst[0] = pk_bf16(v4[0], v4[1]);
        dst[1] = pk_bf16(v4[2], v4[3]);
        xreg = *(const f32x4*)(xr + CHUNK * IN_DIM + rem);
    }
    __syncthreads();

    // ---- seed quad 0: zx4 for quads walks 1 KB per quad through 16 KB ----
    const char* xb = (const char*)xq;
    s16x8 zx4r = *(const s16x8*)(xb + lane * 16);           // quad 0
    f32x4 accA[4], accB[4];
    #pragma unroll
    for (int g = 0; g < 4; ++g)
        accA[g] = __builtin_amdgcn_mfma_f32_16x16x32_bf16(wfrag[g][4], zx4r, biasC[g], 0, 0, 0);
    zx4r = *(const s16x8*)(xb + 1024 + lane * 16);          // quad 1
    int xqoff = 2 * 1024 + lane * 16;                       // next prefetch: quad 2

    const char* hb = (const char*)h_frag;
    unsigned short* hw = (unsigned short*)h_frag;

    // one phase = one timestep.  acc: current quad's gates; accn: next quad's
    // seeds (gate P reseeded at phase P).
    auto phaseF = [&](auto Pc, f32x4 (&acc)[4], f32x4 (&accn)[4]) {
        constexpr int P = decltype(Pc)::value;
        s16x8 zf[4];
        #pragma unroll
        for (int kf = 0; kf < 4; ++kf)
            zf[kf] = *(const s16x8*)(hb + hoffP[P] + kf * 256);

        // ---- P1: g,i,f chains interleaved (12 MFMA — pure matrix phase) ----
        #pragma unroll
        for (int kf = 0; kf < 4; ++kf) {
            acc[2] = __builtin_amdgcn_mfma_f32_16x16x32_bf16(wfrag[2][kf], zf[kf], acc[2], 0, 0, 0);
            acc[0] = __builtin_amdgcn_mfma_f32_16x16x32_bf16(wfrag[0][kf], zf[kf], acc[0], 0, 0, 0);
            acc[1] = __builtin_amdgcn_mfma_f32_16x16x32_bf16(wfrag[1][kf], zf[kf], acc[1], 0, 0, 0);
        }
        __builtin_amdgcn_sched_barrier(0);

        // ---- P2: o-chain (4 dep MFMA) || packs+exp2 + c-numerator ----
        acc[3] = __builtin_amdgcn_mfma_f32_16x16x32_bf16(wfrag[3][0], zf[0], acc[3], 0, 0, 0);
        acc[3] = __builtin_amdgcn_mfma_f32_16x16x32_bf16(wfrag[3][1], zf[1], acc[3], 0, 0, 0);
        acc[3] = __builtin_amdgcn_mfma_f32_16x16x32_bf16(wfrag[3][2], zf[2], acc[3], 0, 0, 0);
        acc[3] = __builtin_amdgcn_mfma_f32_16x16x32_bf16(wfrag[3][3], zf[3], acc[3], 0, 0, 0);
        const float dg = pack4p<P>(acc[2]);
        const float eg = __builtin_amdgcn_exp2f(dg);
        const float di = pack4p<P>(acc[0]);
        const float ei = __builtin_amdgcn_exp2f(di);
        const float df = pack4p<P>(acc[1]);
        const float ef = __builtin_amdgcn_exp2f(df);
        const float af  = 1.0f + ef;
        const float t1  = (1.0f + ei) * (1.0f + eg);
        const float num = fmaf(c_st, t1, (1.0f - eg) * af);
        const float den = af * t1;
        const float dojj = pack4p<P>(acc[3]);
        const float eo  = __builtin_amdgcn_exp2f(dojj);
        const float p_o = 1.0f + eo;
        #pragma unroll
        for (int kq = 0; kq < 4; ++kq) {
            __builtin_amdgcn_sched_group_barrier(0x008, 1, 0);  // 1 MFMA
            __builtin_amdgcn_sched_group_barrier(0x002, 6, 0);  // 6 VALU
        }
        __builtin_amdgcn_sched_barrier(0);

        // ---- P3: serial tail covered by next-quad gate-P reseed MFMA ----
        accn[P] = __builtin_amdgcn_mfma_f32_16x16x32_bf16(wfrag[P][4], zx4r, biasC[P], 0, 0, 0);
        const float cn = num * __builtin_amdgcn_rcpf(den);
        c_st = cn;
        const float ec = __builtin_amdgcn_exp2f(fminf(cn * (2.0f * kNL2E), 40.f));
        const float hn = (1.0f - ec) * __builtin_amdgcn_rcpf(p_o * (1.0f + ec));
        h_ep = hn;
        hw[P * 512 + waddr] = (unsigned short)pk_bf16(hn, hn);
        if constexpr (P == 3) {
            // prefetch zx4 for quad Q+2 (consumed by next quad's reseeds)
            zx4r = *(const s16x8*)(xb + xqoff);
            xqoff = (xqoff + 1024) & 16383;
        }
        __syncthreads();
    };

    auto maint = [&](int Q) {
        const int qi = Q & 7;
        const int chunkI = Q >> 3;
        if (qi < 2) {
            if (chunkI < (T_LEN / CHUNK) - 1) {
                const int flat4 = tid * 4;
                const int b_loc = flat4 >> 9;
                const int rem   = flat4 & 511;
                const int slot = rem >> 4, f = rem & 15;
                const int qs = slot >> 2, s = slot & 3;
                const int nb1 = (chunkI + 1) & 1;
                const int k0 = f + 2 * qi;
                unsigned* dst = (unsigned*)&xq[nb1 * 4096 + qs * 512 + (k0 >> 3) * 128 + (4 * s + b_loc) * 8 + (k0 & 7)];
                dst[0] = pk_bf16(xreg[2 * qi], xreg[2 * qi + 1]);
            }
        } else if (qi == 4) {
            const int tnext = (chunkI + 2) * CHUNK;
            if (tnext < T_LEN) {
                const int flat4 = tid * 4;
                const int b_loc = flat4 >> 9;
                const int rem   = flat4 & 511;
                xreg = *(const f32x4*)(x + (size_t)(b0 + b_loc) * (T_LEN * IN_DIM)
                                         + (size_t)tnext * IN_DIM + rem);
            }
        }
    };

    for (int Q = 0; Q < T_LEN / 4; Q += 2) {
        phaseF(std::integral_constant<int, 0>{}, accA, accB);
        maint(Q);
        phaseF(std::integral_constant<int, 1>{}, accA, accB);
        phaseF(std::integral_constant<int, 2>{}, accA, accB);
        phaseF(std::integral_constant<int, 3>{}, accA, accB);
        phaseF(std::integral_constant<int, 0>{}, accB, accA);
        maint(Q + 1);
        phaseF(std::integral_constant<int, 1>{}, accB, accA);
        phaseF(std::integral_constant<int, 2>{}, accB, accA);
        phaseF(std::integral_constant<int, 3>{}, accB, accA);
    }

    // ---- epilogue: out[b] = sum_cols h * fc_w + fc_b ----
    float v = h_ep * fc_w[col];
    v += __shfl_xor(v, 4);
    v += __shfl_xor(v, 8);
    v += __shfl_xor(v, 16);
    v += __shfl_xor(v, 32);
    if (tid < NROWS) red[tid] = 0.0f;
    __syncthreads();
    if (lane < NROWS) atomicAdd(&red[nb], v);
    __syncthreads();
    if (tid < NROWS) out[b0 + tid] = red[tid] + fc_b[0];
}

extern "C" void kernel_launch(void* const* d_in, const int* in_sizes, int n_in,
                              void* d_out, int out_size, void* d_ws, size_t ws_size,
                              hipStream_t stream) {
    const float* x    = (const float*)d_in[0];
    const float* W_ih = (const float*)d_in[1];
    const float* W_hh = (const float*)d_in[2];
    const float* b_ih = (const float*)d_in[3];
    const float* b_hh = (const float*)d_in[4];
    const float* fc_w = (const float*)d_in[5];
    const float* fc_b = (const float*)d_in[6];
    float* out = (float*)d_out;

    slstm_persistent<<<256, 512, 0, stream>>>(x, W_ih, W_hh, b_ih, b_hh, fc_w, fc_b, out);
}